// Round 8
// baseline (606.207 us; speedup 1.0000x reference)
//
#include <hip/hip_runtime.h>
#include <hip/hip_bf16.h>
#include <cstdint>
#include <cstddef>

#define B_ 64
#define S_ 2048
#define H_ 512

typedef __bf16 bf16x8 __attribute__((ext_vector_type(8)));
typedef float  f32x4  __attribute__((ext_vector_type(4)));

#define AS_GLB __attribute__((address_space(1)))
#define AS_LDS __attribute__((address_space(3)))

__device__ __forceinline__ float fast_tanh(float x) {
    float e = __expf(2.0f * x);
    return 1.0f - __fdividef(2.0f, e + 1.0f);
}

// ---------------------------------------------------------------------------
// enc f32 -> bf16, streaming. 4096 blocks x 256 thr x 8 iters x 8 elems.
// ---------------------------------------------------------------------------
__global__ __launch_bounds__(256) void conv_kernel(const float* __restrict__ enc,
                                                   unsigned short* __restrict__ encb) {
    size_t base = ((size_t)blockIdx.x * 256 + threadIdx.x) * 8;
#pragma unroll
    for (int it = 0; it < 8; ++it) {
        size_t idx = base + (size_t)it * 8388608;   // 4096*256*8
        float4 a = *(const float4*)(enc + idx);
        float4 c = *(const float4*)(enc + idx + 4);
        bf16x8 v;
        v[0] = (__bf16)a.x; v[1] = (__bf16)a.y; v[2] = (__bf16)a.z; v[3] = (__bf16)a.w;
        v[4] = (__bf16)c.x; v[5] = (__bf16)c.y; v[6] = (__bf16)c.z; v[7] = (__bf16)c.w;
        *(bf16x8*)(encb + idx) = v;
    }
}

// ---------------------------------------------------------------------------
// prep: blocks 0..255  : W1 [k][n] f32 -> Wt [n][k] bf16 (transpose+downcast)
//       blocks 256..383: cvals[b][h] = b1[h]+b2[h]+ hidden[b,:]·W2[:,h]
// ---------------------------------------------------------------------------
__global__ __launch_bounds__(256) void prep_kernel(const float* __restrict__ W1,
                                                   unsigned short* __restrict__ Wt,
                                                   const float* __restrict__ hidden,
                                                   const float* __restrict__ W2,
                                                   const float* __restrict__ b1,
                                                   const float* __restrict__ b2,
                                                   float* __restrict__ cvals) {
    if (blockIdx.x < 256) {
        __shared__ float tile[32][33];
        int tn = blockIdx.x >> 4;
        int tk = blockIdx.x & 15;
        int lx = threadIdx.x & 31;
        int ly = threadIdx.x >> 5;
#pragma unroll
        for (int i = 0; i < 4; ++i) {
            int k = tk * 32 + ly + i * 8;
            tile[ly + i * 8][lx] = W1[k * H_ + tn * 32 + lx];
        }
        __syncthreads();
#pragma unroll
        for (int i = 0; i < 4; ++i) {
            int n = tn * 32 + ly + i * 8;
            float v = tile[lx][ly + i * 8];
            __bf16 bv = (__bf16)v;
            Wt[(size_t)n * H_ + tk * 32 + lx] = *(unsigned short*)&bv;
        }
    } else {
        int blk = blockIdx.x - 256;          // 0..127
        int b = blk >> 1;
        int h = (blk & 1) * 256 + threadIdx.x;
        float acc = b1[h] + b2[h];
        const float* hp = hidden + b * H_;
        const float* wp = W2 + h;
#pragma unroll 16
        for (int k = 0; k < H_; ++k) acc = fmaf(hp[k], wp[(size_t)k * H_], acc);
        cvals[b * H_ + h] = acc;
    }
}

// ---------------------------------------------------------------------------
// m97-structure score: pure bf16 GEMM + tanh·V epilogue.
// 128x128 tile, BK=64, 4 waves; BOTH operands via global_load_lds width=16,
// linear LDS dbuf (64 KB), one barrier per k-step.
// ---------------------------------------------------------------------------
__global__ __launch_bounds__(256) void score97_kernel(const unsigned short* __restrict__ encb,
                                                      const unsigned short* __restrict__ Wt,
                                                      const float* __restrict__ cvals,
                                                      const float* __restrict__ Vp,
                                                      float* __restrict__ logits) {
    __shared__ __align__(16) unsigned short As[2][128][64];
    __shared__ __align__(16) unsigned short Bs[2][128][64];

    // XCD-bijective swizzle: 4096 % 8 == 0
    int orig = blockIdx.x;
    int wg   = (orig & 7) * 512 + (orig >> 3);
    int b     = wg >> 6;
    int stile = (wg >> 2) & 15;
    int ntile = wg & 3;

    int tid  = threadIdx.x;
    int wid  = tid >> 6;
    int lane = tid & 63;
    int wm = wid >> 1, wn = wid & 1;
    int rsel = lane & 15;
    int g    = lane >> 4;

    f32x4 acc[4][4];
#pragma unroll
    for (int m = 0; m < 4; ++m)
#pragma unroll
        for (int n = 0; n < 4; ++n) acc[m][n] = (f32x4){0.f, 0.f, 0.f, 0.f};

    const unsigned short* Abase = encb + ((size_t)(b * S_ + stile * 128)) * H_;
    const unsigned short* Bbase = Wt + ((size_t)(ntile * 128)) * H_;

    int lrow = lane >> 3;          // 0..7
    int lcol = (lane & 7) * 8;     // elem col within 64

    auto stage = [&](int nb, int kt) {
        int kk = kt * 64;
#pragma unroll
        for (int i = 0; i < 4; ++i) {
            int chunk = wid * 4 + i;           // 0..15 (8 rows each)
            int row = chunk * 8 + lrow;
            __builtin_amdgcn_global_load_lds(
                (const AS_GLB unsigned int*)(Abase + (size_t)row * H_ + kk + lcol),
                (AS_LDS unsigned int*)&As[nb][chunk * 8][0], 16, 0, 0);
            __builtin_amdgcn_global_load_lds(
                (const AS_GLB unsigned int*)(Bbase + (size_t)row * H_ + kk + lcol),
                (AS_LDS unsigned int*)&Bs[nb][chunk * 8][0], 16, 0, 0);
        }
    };
    auto compute = [&](int cb) {
#pragma unroll
        for (int ks = 0; ks < 2; ++ks) {
            int kof = ks * 32 + g * 8;
            bf16x8 af[4], bfr[4];
#pragma unroll
            for (int m = 0; m < 4; ++m)
                af[m] = *(const bf16x8*)&As[cb][wm * 64 + m * 16 + rsel][kof];
#pragma unroll
            for (int n = 0; n < 4; ++n)
                bfr[n] = *(const bf16x8*)&Bs[cb][wn * 64 + n * 16 + rsel][kof];
#pragma unroll
            for (int m = 0; m < 4; ++m)
#pragma unroll
                for (int n = 0; n < 4; ++n)
                    acc[m][n] = __builtin_amdgcn_mfma_f32_16x16x32_bf16(
                        af[m], bfr[n], acc[m][n], 0, 0, 0);
        }
    };

    stage(0, 0);
    __syncthreads();
    for (int kt = 0; kt < 8; ++kt) {
        int cur = kt & 1;
        if (kt < 7) stage(cur ^ 1, kt + 1);
        compute(cur);
        __syncthreads();
    }

    // epilogue: tanh + V-dot + 16-lane row reduce + atomic partial logits
    int csel = rsel;
    float cw[4], vv[4];
#pragma unroll
    for (int n = 0; n < 4; ++n) {
        int col = ntile * 128 + wn * 64 + n * 16 + csel;
        cw[n] = cvals[b * H_ + col];
        vv[n] = Vp[col];
    }
    float part[16];
#pragma unroll
    for (int m = 0; m < 4; ++m)
#pragma unroll
        for (int r = 0; r < 4; ++r) {
            float p = 0.f;
#pragma unroll
            for (int n = 0; n < 4; ++n) {
                float s = fast_tanh(acc[m][n][r] + cw[n]);
                p = fmaf(vv[n], s, p);
            }
            part[m * 4 + r] = p;
        }
#pragma unroll
    for (int i = 0; i < 16; ++i)
#pragma unroll
        for (int off = 1; off < 16; off <<= 1)
            part[i] += __shfl_xor(part[i], off);

    if (csel == 0) {
        int gq = lane >> 4;
#pragma unroll
        for (int m = 0; m < 4; ++m)
#pragma unroll
            for (int r = 0; r < 4; ++r) {
                int row = stile * 128 + wm * 64 + m * 16 + gq * 4 + r;
                atomicAdd(&logits[b * S_ + row], part[m * 4 + r]);
            }
    }
}

// ---------------------------------------------------------------------------
// FALLBACK score (round-7, measured 227 us): f32 A reg-staged, BK=32,
// interleaved dbuf + XOR swizzle, 32 KB LDS.
// ---------------------------------------------------------------------------
__global__ __launch_bounds__(256, 4) void score_kernel(const float* __restrict__ enc,
                                                       const unsigned short* __restrict__ Wt,
                                                       const float* __restrict__ cvals,
                                                       const float* __restrict__ Vp,
                                                       float* __restrict__ logits) {
    __shared__ __align__(16) unsigned short As[128 * 64];
    __shared__ __align__(16) unsigned short Bs[128 * 64];

    int orig = blockIdx.x;
    int wg   = (orig & 7) * 512 + (orig >> 3);
    int b     = wg >> 6;
    int stile = (wg >> 2) & 15;
    int ntile = wg & 3;

    int tid  = threadIdx.x;
    int wid  = tid >> 6;
    int lane = tid & 63;
    int wm = wid >> 1, wn = wid & 1;
    int rsel = lane & 15;
    int g    = lane >> 4;

    f32x4 acc[4][4];
#pragma unroll
    for (int m = 0; m < 4; ++m)
#pragma unroll
        for (int n = 0; n < 4; ++n) acc[m][n] = (f32x4){0.f, 0.f, 0.f, 0.f};

    const float*          Abase = enc + ((size_t)(b * S_ + stile * 128)) * H_;
    const unsigned short* Bbase = Wt + ((size_t)(ntile * 128)) * H_;

    int srow = tid >> 1;
    int shalf = (tid & 1);
    int c0 = shalf * 2;

    float4 ra[4];
    bf16x8 rb[2];

    auto swz = [&](int row, int nbc) -> int {
        return row * 64 + ((nbc ^ (row & 7)) << 3);
    };

    auto loadAB = [&](int kt) {
        const float* ap = Abase + (size_t)srow * H_ + kt * 32 + shalf * 16;
        ra[0] = *(const float4*)(ap);
        ra[1] = *(const float4*)(ap + 4);
        ra[2] = *(const float4*)(ap + 8);
        ra[3] = *(const float4*)(ap + 12);
        const unsigned short* bp = Bbase + (size_t)srow * H_ + kt * 32 + shalf * 16;
        rb[0] = *(const bf16x8*)(bp);
        rb[1] = *(const bf16x8*)(bp + 8);
    };
    auto writeAB = [&](int nb) {
        bf16x8 va[2];
        const float* f = (const float*)&ra[0];
#pragma unroll
        for (int j = 0; j < 2; ++j)
#pragma unroll
            for (int i = 0; i < 8; ++i) va[j][i] = (__bf16)f[j * 8 + i];
#pragma unroll
        for (int j = 0; j < 2; ++j) {
            int idx = swz(srow, nb * 4 + c0 + j);
            *(bf16x8*)&As[idx] = va[j];
            *(bf16x8*)&Bs[idx] = rb[j];
        }
    };
    auto compute = [&](int cb) {
        bf16x8 af[4], bfr[4];
#pragma unroll
        for (int m = 0; m < 4; ++m) {
            int row = wm * 64 + m * 16 + rsel;
            af[m] = *(const bf16x8*)&As[swz(row, cb * 4 + g)];
        }
#pragma unroll
        for (int n = 0; n < 4; ++n) {
            int row = wn * 64 + n * 16 + rsel;
            bfr[n] = *(const bf16x8*)&Bs[swz(row, cb * 4 + g)];
        }
#pragma unroll
        for (int m = 0; m < 4; ++m)
#pragma unroll
            for (int n = 0; n < 4; ++n)
                acc[m][n] = __builtin_amdgcn_mfma_f32_16x16x32_bf16(
                    af[m], bfr[n], acc[m][n], 0, 0, 0);
    };

    loadAB(0);
    writeAB(0);
    __syncthreads();

    for (int kt = 0; kt < 16; ++kt) {
        int cur = kt & 1;
        if (kt < 15) loadAB(kt + 1);
        compute(cur);
        if (kt < 15) writeAB(cur ^ 1);
        __syncthreads();
    }

    int csel = rsel;
    float cw[4], vv[4];
#pragma unroll
    for (int n = 0; n < 4; ++n) {
        int col = ntile * 128 + wn * 64 + n * 16 + csel;
        cw[n] = cvals[b * H_ + col];
        vv[n] = Vp[col];
    }
    float part[16];
#pragma unroll
    for (int m = 0; m < 4; ++m)
#pragma unroll
        for (int r = 0; r < 4; ++r) {
            float p = 0.f;
#pragma unroll
            for (int n = 0; n < 4; ++n) {
                float s = fast_tanh(acc[m][n][r] + cw[n]);
                p = fmaf(vv[n], s, p);
            }
            part[m * 4 + r] = p;
        }
#pragma unroll
    for (int i = 0; i < 16; ++i)
#pragma unroll
        for (int off = 1; off < 16; off <<= 1)
            part[i] += __shfl_xor(part[i], off);

    if (csel == 0) {
        int gq = lane >> 4;
#pragma unroll
        for (int m = 0; m < 4; ++m)
#pragma unroll
            for (int r = 0; r < 4; ++r) {
                int row = stile * 128 + wm * 64 + m * 16 + gq * 4 + r;
                atomicAdd(&logits[b * S_ + row], part[m * 4 + r]);
            }
    }
}

// ---------------------------------------------------------------------------
// softmax over s per b
// ---------------------------------------------------------------------------
__global__ __launch_bounds__(256) void softmax_kernel(const float* __restrict__ logits,
                                                      float* __restrict__ wout) {
    int b = blockIdx.x;
    int t = threadIdx.x;
    __shared__ float red[8];
    float v[8];
#pragma unroll
    for (int i = 0; i < 8; ++i) v[i] = logits[b * S_ + t + i * 256];
    float m = v[0];
#pragma unroll
    for (int i = 1; i < 8; ++i) m = fmaxf(m, v[i]);
#pragma unroll
    for (int off = 32; off >= 1; off >>= 1) m = fmaxf(m, __shfl_xor(m, off));
    int wid = t >> 6, lane = t & 63;
    if (lane == 0) red[wid] = m;
    __syncthreads();
    m = fmaxf(fmaxf(red[0], red[1]), fmaxf(red[2], red[3]));
    float s = 0.f;
#pragma unroll
    for (int i = 0; i < 8; ++i) { v[i] = __expf(v[i] - m); s += v[i]; }
#pragma unroll
    for (int off = 32; off >= 1; off >>= 1) s += __shfl_xor(s, off);
    if (lane == 0) red[4 + wid] = s;
    __syncthreads();
    float tot = red[4] + red[5] + red[6] + red[7];
    float inv = __fdividef(1.0f, tot);
#pragma unroll
    for (int i = 0; i < 8; ++i) wout[b * S_ + t + i * 256] = v[i] * inv;
}

// ---------------------------------------------------------------------------
// context[b][h] = sum_s w[b][s] * enc[b][s][h]
// ---------------------------------------------------------------------------
__global__ __launch_bounds__(512) void context_kernel(const float* __restrict__ enc,
                                                      const float* __restrict__ w,
                                                      float* __restrict__ ctx) {
    int b  = blockIdx.x >> 4;
    int sc = blockIdx.x & 15;
    int h  = threadIdx.x;
    const float* ep = enc + ((size_t)(b * S_ + sc * 128)) * H_ + h;
    const float* wp = w + b * S_ + sc * 128;
    float acc = 0.f;
#pragma unroll 8
    for (int i = 0; i < 128; ++i) acc = fmaf(wp[i], ep[(size_t)i * H_], acc);
    atomicAdd(&ctx[b * H_ + h], acc);
}

// ---------------------------------------------------------------------------
extern "C" void kernel_launch(void* const* d_in, const int* in_sizes, int n_in,
                              void* d_out, int out_size, void* d_ws, size_t ws_size,
                              hipStream_t stream) {
    (void)in_sizes; (void)n_in; (void)out_size;
    const float* enc    = (const float*)d_in[0];
    const float* hidden = (const float*)d_in[1];
    const float* W1     = (const float*)d_in[2];
    const float* b1     = (const float*)d_in[3];
    const float* W2     = (const float*)d_in[4];
    const float* b2     = (const float*)d_in[5];
    const float* Vp     = (const float*)d_in[6];
    // d_in[7] (bV) unused: softmax is shift-invariant and logits are not an output.

    char* ws = (char*)d_ws;
    unsigned short* Wt = (unsigned short*)ws;                    // 512 KB
    float* cvals  = (float*)(ws + 524288);                       // 128 KB
    float* logits = (float*)(ws + 524288 + 131072);              // 512 KB
    unsigned short* encb = (unsigned short*)(ws + 2097152);      // 134.2 MB (if available)

    const size_t need = 2097152 + (size_t)B_ * S_ * H_ * 2;
    const bool big = ws_size >= need;

    float* ctx  = (float*)d_out;          // [64,512]
    float* wout = ctx + B_ * H_;          // [64,2048,1]

    hipMemsetAsync(logits, 0, (size_t)B_ * S_ * sizeof(float), stream);
    hipMemsetAsync(ctx,    0, (size_t)B_ * H_ * sizeof(float), stream);

    prep_kernel<<<384, 256, 0, stream>>>(W1, Wt, hidden, W2, b1, b2, cvals);
    if (big) {
        conv_kernel<<<4096, 256, 0, stream>>>(enc, encb);
        score97_kernel<<<4096, 256, 0, stream>>>(encb, Wt, cvals, Vp, logits);
    } else {
        score_kernel<<<4096, 256, 0, stream>>>(enc, Wt, cvals, Vp, logits);
    }
    softmax_kernel<<<64, 256, 0, stream>>>(logits, wout);
    context_kernel<<<1024, 512, 0, stream>>>(enc, wout, ctx);
}

// Round 10
// 566.081 us; speedup vs baseline: 1.0709x; 1.0709x over previous
//
#include <hip/hip_runtime.h>
#include <hip/hip_bf16.h>
#include <cstdint>
#include <cstddef>

#define B_ 64
#define S_ 2048
#define H_ 512

typedef __bf16 bf16x8 __attribute__((ext_vector_type(8)));
typedef float  f32x4  __attribute__((ext_vector_type(4)));

#define AS_GLB __attribute__((address_space(1)))
#define AS_LDS __attribute__((address_space(3)))

__device__ __forceinline__ float fast_tanh(float x) {
    float e = __expf(2.0f * x);
    return 1.0f - __fdividef(2.0f, e + 1.0f);
}

// ---------------------------------------------------------------------------
// prep: blocks 0..255  : W1 [k][n] f32 -> Wt [n][k] bf16 (transpose+downcast)
//       blocks 256..383: cvals[b][h] = b1[h]+b2[h]+ hidden[b,:]·W2[:,h]
// ---------------------------------------------------------------------------
__global__ __launch_bounds__(256) void prep_kernel(const float* __restrict__ W1,
                                                   unsigned short* __restrict__ Wt,
                                                   const float* __restrict__ hidden,
                                                   const float* __restrict__ W2,
                                                   const float* __restrict__ b1,
                                                   const float* __restrict__ b2,
                                                   float* __restrict__ cvals) {
    if (blockIdx.x < 256) {
        __shared__ float tile[32][33];
        int tn = blockIdx.x >> 4;
        int tk = blockIdx.x & 15;
        int lx = threadIdx.x & 31;
        int ly = threadIdx.x >> 5;
#pragma unroll
        for (int i = 0; i < 4; ++i) {
            int k = tk * 32 + ly + i * 8;
            tile[ly + i * 8][lx] = W1[k * H_ + tn * 32 + lx];
        }
        __syncthreads();
#pragma unroll
        for (int i = 0; i < 4; ++i) {
            int n = tn * 32 + ly + i * 8;
            float v = tile[lx][ly + i * 8];
            __bf16 bv = (__bf16)v;
            Wt[(size_t)n * H_ + tk * 32 + lx] = *(unsigned short*)&bv;
        }
    } else {
        int blk = blockIdx.x - 256;          // 0..127
        int b = blk >> 1;
        int h = (blk & 1) * 256 + threadIdx.x;
        float acc = b1[h] + b2[h];
        const float* hp = hidden + b * H_;
        const float* wp = W2 + h;
#pragma unroll 16
        for (int k = 0; k < H_; ++k) acc = fmaf(hp[k], wp[(size_t)k * H_], acc);
        cvals[b * H_ + h] = acc;
    }
}

// ---------------------------------------------------------------------------
// score97b: fused GEMM + tanh·V epilogue.
// 128x128 tile, BK=32, 4 waves, mfma 16x16x32 bf16.
// A staged as RAW F32 via global_load_lds (source-address XOR-swizzled so the
// 128B f32 rows read conflict-free); converted f32->bf16 at fragment read.
// B staged bf16 via global_load_lds, linear (64B rows: naturally conflict-free).
// LDS 48 KB -> 3 blocks/CU. One barrier per k-step, stage-before-compute.
// ---------------------------------------------------------------------------
__global__ __launch_bounds__(256, 3) void score97b_kernel(const float* __restrict__ enc,
                                                          const unsigned short* __restrict__ Wt,
                                                          const float* __restrict__ cvals,
                                                          const float* __restrict__ Vp,
                                                          float* __restrict__ logits) {
    __shared__ __align__(16) float          Asf[2][128][32];   // 32 KB
    __shared__ __align__(16) unsigned short Bsh[2][128][32];   // 16 KB

    // XCD-bijective swizzle (4096 % 8 == 0): the 4 ntile siblings sharing an
    // A-panel get consecutive wg on the same XCD -> panel L2-shared.
    int orig = blockIdx.x;
    int wg   = (orig & 7) * 512 + (orig >> 3);
    int b     = wg >> 6;
    int stile = (wg >> 2) & 15;
    int ntile = wg & 3;

    int tid  = threadIdx.x;
    int wid  = tid >> 6;
    int lane = tid & 63;
    int wm = wid >> 1, wn = wid & 1;
    int rsel = lane & 15;
    int g    = lane >> 4;

    f32x4 acc[4][4];
#pragma unroll
    for (int m = 0; m < 4; ++m)
#pragma unroll
        for (int n = 0; n < 4; ++n) acc[m][n] = (f32x4){0.f, 0.f, 0.f, 0.f};

    const float*          Abase = enc + ((size_t)(b * S_ + stile * 128)) * H_;
    const unsigned short* Bbase = Wt + ((size_t)(ntile * 128)) * H_;

    // A staging geometry: 4 issues x (4 waves x 1KB). lane covers 16B chunk.
    int arow0 = (lane >> 3);          // + i*32 + wid*8
    int ac    = lane & 7;             // logical LDS chunk (4 f32)
    // B staging geometry: 2 issues. row = i*64 + wid*16 + (lane>>2), chunk=lane&3.
    int brow0 = (lane >> 2);
    int bc    = lane & 3;

    auto stage = [&](int nb, int kt) {
#pragma unroll
        for (int i = 0; i < 4; ++i) {
            int row = i * 32 + wid * 8 + arow0;
            // source chunk pre-swizzled: LDS chunk ac holds global chunk ac^(row&7)
            const float* src = Abase + (size_t)row * H_ + kt * 32 + ((ac ^ (row & 7)) << 2);
            __builtin_amdgcn_global_load_lds((const AS_GLB unsigned int*)src,
                                             (AS_LDS unsigned int*)&Asf[nb][i * 32 + wid * 8][0],
                                             16, 0, 0);
        }
#pragma unroll
        for (int i = 0; i < 2; ++i) {
            int row = i * 64 + wid * 16 + brow0;
            const unsigned short* src = Bbase + (size_t)row * H_ + kt * 32 + bc * 8;
            __builtin_amdgcn_global_load_lds((const AS_GLB unsigned int*)src,
                                             (AS_LDS unsigned int*)&Bsh[nb][i * 64 + wid * 16][0],
                                             16, 0, 0);
        }
    };

    auto compute = [&](int cb) {
        bf16x8 af[4], bfr[4];
#pragma unroll
        for (int m = 0; m < 4; ++m) {
            int row = wm * 64 + m * 16 + rsel;
            int r7  = row & 7;
            f32x4 lo = *(const f32x4*)&Asf[cb][row][((2 * g) ^ r7) << 2];
            f32x4 hi = *(const f32x4*)&Asf[cb][row][((2 * g + 1) ^ r7) << 2];
#pragma unroll
            for (int j = 0; j < 4; ++j) {
                af[m][j]     = (__bf16)lo[j];
                af[m][4 + j] = (__bf16)hi[j];
            }
        }
#pragma unroll
        for (int n = 0; n < 4; ++n) {
            int row = wn * 64 + n * 16 + rsel;
            bfr[n] = *(const bf16x8*)&Bsh[cb][row][g * 8];
        }
#pragma unroll
        for (int m = 0; m < 4; ++m)
#pragma unroll
            for (int n = 0; n < 4; ++n)
                acc[m][n] = __builtin_amdgcn_mfma_f32_16x16x32_bf16(
                    af[m], bfr[n], acc[m][n], 0, 0, 0);
    };

    stage(0, 0);
    __syncthreads();
    for (int kt = 0; kt < 16; ++kt) {
        int cur = kt & 1;
        if (kt < 15) stage(cur ^ 1, kt + 1);
        compute(cur);
        __syncthreads();
    }

    // epilogue: tanh + V-dot + 16-lane row reduce + atomic partial logits
    int csel = rsel;
    float cw[4], vv[4];
#pragma unroll
    for (int n = 0; n < 4; ++n) {
        int col = ntile * 128 + wn * 64 + n * 16 + csel;
        cw[n] = cvals[b * H_ + col];
        vv[n] = Vp[col];
    }
    float part[16];
#pragma unroll
    for (int m = 0; m < 4; ++m)
#pragma unroll
        for (int r = 0; r < 4; ++r) {
            float p = 0.f;
#pragma unroll
            for (int n = 0; n < 4; ++n) {
                float s = fast_tanh(acc[m][n][r] + cw[n]);
                p = fmaf(vv[n], s, p);
            }
            part[m * 4 + r] = p;
        }
#pragma unroll
    for (int i = 0; i < 16; ++i)
#pragma unroll
        for (int off = 1; off < 16; off <<= 1)
            part[i] += __shfl_xor(part[i], off);

    if (csel == 0) {
        int gq = lane >> 4;
#pragma unroll
        for (int m = 0; m < 4; ++m)
#pragma unroll
            for (int r = 0; r < 4; ++r) {
                int row = stile * 128 + wm * 64 + m * 16 + gq * 4 + r;
                atomicAdd(&logits[b * S_ + row], part[m * 4 + r]);
            }
    }
}

// ---------------------------------------------------------------------------
// softmax over s per b
// ---------------------------------------------------------------------------
__global__ __launch_bounds__(256) void softmax_kernel(const float* __restrict__ logits,
                                                      float* __restrict__ wout) {
    int b = blockIdx.x;
    int t = threadIdx.x;
    __shared__ float red[8];
    float v[8];
#pragma unroll
    for (int i = 0; i < 8; ++i) v[i] = logits[b * S_ + t + i * 256];
    float m = v[0];
#pragma unroll
    for (int i = 1; i < 8; ++i) m = fmaxf(m, v[i]);
#pragma unroll
    for (int off = 32; off >= 1; off >>= 1) m = fmaxf(m, __shfl_xor(m, off));
    int wid = t >> 6, lane = t & 63;
    if (lane == 0) red[wid] = m;
    __syncthreads();
    m = fmaxf(fmaxf(red[0], red[1]), fmaxf(red[2], red[3]));
    float s = 0.f;
#pragma unroll
    for (int i = 0; i < 8; ++i) { v[i] = __expf(v[i] - m); s += v[i]; }
#pragma unroll
    for (int off = 32; off >= 1; off >>= 1) s += __shfl_xor(s, off);
    if (lane == 0) red[4 + wid] = s;
    __syncthreads();
    float tot = red[4] + red[5] + red[6] + red[7];
    float inv = __fdividef(1.0f, tot);
#pragma unroll
    for (int i = 0; i < 8; ++i) wout[b * S_ + t + i * 256] = v[i] * inv;
}

// ---------------------------------------------------------------------------
// context[b][h] = sum_s w[b][s] * enc[b][s][h]
// 2048 blocks x 64 rows: shorter dependent chains, more blocks/CU.
// ---------------------------------------------------------------------------
__global__ __launch_bounds__(512) void context_kernel(const float* __restrict__ enc,
                                                      const float* __restrict__ w,
                                                      float* __restrict__ ctx) {
    int b  = blockIdx.x >> 5;
    int sc = blockIdx.x & 31;
    int h  = threadIdx.x;
    const float* ep = enc + ((size_t)(b * S_ + sc * 64)) * H_ + h;
    const float* wp = w + b * S_ + sc * 64;
    float acc = 0.f;
#pragma unroll 8
    for (int i = 0; i < 64; ++i) acc = fmaf(wp[i], ep[(size_t)i * H_], acc);
    atomicAdd(&ctx[b * H_ + h], acc);
}

// ---------------------------------------------------------------------------
extern "C" void kernel_launch(void* const* d_in, const int* in_sizes, int n_in,
                              void* d_out, int out_size, void* d_ws, size_t ws_size,
                              hipStream_t stream) {
    (void)in_sizes; (void)n_in; (void)out_size; (void)ws_size;
    const float* enc    = (const float*)d_in[0];
    const float* hidden = (const float*)d_in[1];
    const float* W1     = (const float*)d_in[2];
    const float* b1     = (const float*)d_in[3];
    const float* W2     = (const float*)d_in[4];
    const float* b2     = (const float*)d_in[5];
    const float* Vp     = (const float*)d_in[6];
    // d_in[7] (bV) unused: softmax is shift-invariant and logits are not an output.

    char* ws = (char*)d_ws;
    unsigned short* Wt = (unsigned short*)ws;                    // 512 KB
    float* cvals  = (float*)(ws + 524288);                       // 128 KB
    float* logits = (float*)(ws + 524288 + 131072);              // 512 KB

    float* ctx  = (float*)d_out;          // [64,512]
    float* wout = ctx + B_ * H_;          // [64,2048,1]

    hipMemsetAsync(logits, 0, (size_t)B_ * S_ * sizeof(float), stream);
    hipMemsetAsync(ctx,    0, (size_t)B_ * H_ * sizeof(float), stream);

    prep_kernel<<<384, 256, 0, stream>>>(W1, Wt, hidden, W2, b1, b2, cvals);
    score97b_kernel<<<4096, 256, 0, stream>>>(enc, Wt, cvals, Vp, logits);
    softmax_kernel<<<64, 256, 0, stream>>>(logits, wout);
    context_kernel<<<2048, 512, 0, stream>>>(enc, wout, ctx);
}